// Round 1
// baseline (654.447 us; speedup 1.0000x reference)
//
#include <hip/hip_runtime.h>

#define SEQ 4096
#define DIM 1280
#define NH 16
#define HD 80
#define HDP 96
#define TDIM 3840

#define SCALE 0.11180339887498948f
#define LOG2E 1.4426950408889634f

typedef __bf16 bf16x8 __attribute__((ext_vector_type(8)));
typedef float f32x4 __attribute__((ext_vector_type(4)));

__device__ __forceinline__ unsigned short f2bf(float f) {
  unsigned int u = __builtin_bit_cast(unsigned int, f);
  u += 0x7FFF + ((u >> 16) & 1);
  return (unsigned short)(u >> 16);
}
__device__ __forceinline__ float bf2f(unsigned short b) {
  unsigned int u = ((unsigned int)b) << 16;
  return __builtin_bit_cast(float, u);
}

__device__ __forceinline__ void gload_lds16(const void* g, void* l) {
  __builtin_amdgcn_global_load_lds(
      (const __attribute__((address_space(1))) unsigned int*)g,
      (__attribute__((address_space(3))) unsigned int*)l, 16, 0, 0);
}

// ---------------- fp32 -> bf16 convert (vectorized) ----------------
__global__ void cvt_bf16(const float* __restrict__ in, unsigned short* __restrict__ out, int n4) {
  int i = blockIdx.x * 256 + threadIdx.x;
  if (i >= n4) return;
  float4 f = ((const float4*)in)[i];
  ushort4 o;
  o.x = f2bf(f.x); o.y = f2bf(f.y); o.z = f2bf(f.z); o.w = f2bf(f.w);
  ((ushort4*)out)[i] = o;
}

// ---------------- cos/sin table ----------------
__global__ void trig_tab(const float* __restrict__ rope, float* __restrict__ ct,
                         float* __restrict__ st, int n) {
  int i = blockIdx.x * 256 + threadIdx.x;
  if (i >= n) return;
  float v = rope[i];
  ct[i] = cosf(v);
  st[i] = sinf(v);
}

// ---------------- GEMM: C = A(MxK) @ B(NxK)^T + bias ----------------
// 128x128 tile, BK=32, 4 waves (2x2), 16x16x32 bf16 MFMA
template <int F32OUT>
__global__ __launch_bounds__(256) void gemm_bt(const unsigned short* __restrict__ A,
                                               const unsigned short* __restrict__ B,
                                               const float* __restrict__ bias,
                                               void* __restrict__ Cout, int M, int N, int K) {
  __shared__ unsigned short As[4096];
  __shared__ unsigned short Bs[4096];
  const int t = threadIdx.x;
  const int l = t & 63, w = t >> 6;
  const int row16 = l & 15, kg = l >> 4;
  const int brow = blockIdx.y * 128, bcol = blockIdx.x * 128;
  const int wr = w >> 1, wc = w & 1;
  f32x4 acc[4][4] = {};
  const size_t Ks = (size_t)K;
  const unsigned short* Ag = A + (brow + (t >> 2)) * Ks + (t & 3) * 8;
  const unsigned short* Bg = B + (bcol + (t >> 2)) * Ks + (t & 3) * 8;
  unsigned short* AsW = As + w * 512;
  unsigned short* BsW = Bs + w * 512;
  const int nk = K >> 5;
  for (int kt = 0; kt < nk; ++kt) {
    const unsigned short* a = Ag + kt * 32;
    const unsigned short* b = Bg + kt * 32;
    gload_lds16(a, AsW);
    gload_lds16(a + 64 * Ks, AsW + 2048);
    gload_lds16(b, BsW);
    gload_lds16(b + 64 * Ks, BsW + 2048);
    __syncthreads();
    bf16x8 af[4], bfr[4];
#pragma unroll
    for (int m = 0; m < 4; ++m)
      af[m] = *(const bf16x8*)&As[(wr * 64 + m * 16 + row16) * 32 + kg * 8];
#pragma unroll
    for (int n = 0; n < 4; ++n)
      bfr[n] = *(const bf16x8*)&Bs[(wc * 64 + n * 16 + row16) * 32 + kg * 8];
#pragma unroll
    for (int m = 0; m < 4; ++m)
#pragma unroll
      for (int n = 0; n < 4; ++n)
        acc[m][n] = __builtin_amdgcn_mfma_f32_16x16x32_bf16(af[m], bfr[n], acc[m][n], 0, 0, 0);
    __syncthreads();
  }
#pragma unroll
  for (int n = 0; n < 4; ++n) {
    const int col = bcol + wc * 64 + n * 16 + row16;
    const float bv = bias[col];
#pragma unroll
    for (int m = 0; m < 4; ++m) {
      const int row = brow + wr * 64 + m * 16 + kg * 4;
#pragma unroll
      for (int r = 0; r < 4; ++r) {
        float v = acc[m][n][r] + bv;
        if (F32OUT)
          ((float*)Cout)[(size_t)(row + r) * N + col] = v;
        else
          ((unsigned short*)Cout)[(size_t)(row + r) * N + col] = f2bf(v);
      }
    }
  }
}

// ---------------- RoPE + repack Q,K -> [h][s][96] (pad 80->96 zeros) ----------------
__global__ void rope_qk(const unsigned short* __restrict__ Y, const float* __restrict__ ct,
                        const float* __restrict__ st, unsigned short* __restrict__ Qr,
                        unsigned short* __restrict__ Kr) {
  const int h = blockIdx.x;
  const int s = blockIdx.y;
  const int d = threadIdx.x;
  if (d >= HDP) return;
  const size_t orow = ((size_t)h * SEQ + s) * HDP + d;
  if (d >= HD) {
    Qr[orow] = 0;
    Kr[orow] = 0;
    return;
  }
  const int dp = d < 40 ? d + 40 : d - 40;
  const float sign = d < 40 ? -1.f : 1.f;
  const unsigned short* yrow = Y + (size_t)s * TDIM;
  const float c = ct[s * HD + d];
  const float sn = st[s * HD + d];
  const float q = bf2f(yrow[h * HD + d]);
  const float qp = bf2f(yrow[h * HD + dp]);
  const float k = bf2f(yrow[DIM + h * HD + d]);
  const float kp = bf2f(yrow[DIM + h * HD + dp]);
  Qr[orow] = f2bf(q * c + sign * qp * sn);
  Kr[orow] = f2bf(k * c + sign * kp * sn);
}

// ---------------- V transpose -> [h][d=80][s] ----------------
__global__ void vtrans(const unsigned short* __restrict__ Y, unsigned short* __restrict__ Vt) {
  const int hd = blockIdx.x;  // 0..1279
  const int h = hd / HD, d = hd % HD;
  const size_t src_col = 2 * DIM + (size_t)h * HD + d;
  for (int s = threadIdx.x; s < SEQ; s += 256)
    Vt[(size_t)hd * SEQ + s] = Y[(size_t)s * TDIM + src_col];
}

// ---------------- Flash attention: 1 wave/block, 16 q-rows, K-tiles of 64 ----------------
__global__ __launch_bounds__(64) void attn(const unsigned short* __restrict__ Qr,
                                           const unsigned short* __restrict__ Kr,
                                           const unsigned short* __restrict__ Vt,
                                           unsigned short* __restrict__ Ob) {
  __shared__ unsigned short P_lds[16 * 64];
  const int l = threadIdx.x;
  const int row16 = l & 15, kg = l >> 4;
  const int h = blockIdx.y;
  const int q0 = blockIdx.x * 16;
  const size_t hs = (size_t)h * SEQ;

  bf16x8 qf[3];
#pragma unroll
  for (int c = 0; c < 3; ++c)
    qf[c] = *(const bf16x8*)&Qr[(hs + q0 + row16) * HDP + c * 32 + kg * 8];

  float mrow[4] = {-1e30f, -1e30f, -1e30f, -1e30f};
  float lrow[4] = {0.f, 0.f, 0.f, 0.f};
  f32x4 oacc[5] = {};

  for (int kb = 0; kb < SEQ / 64; ++kb) {
    const int s0 = kb * 64;
    f32x4 sacc[4] = {};
#pragma unroll
    for (int nb = 0; nb < 4; ++nb) {
      const unsigned short* kbase = &Kr[(hs + s0 + nb * 16 + row16) * HDP + kg * 8];
#pragma unroll
      for (int c = 0; c < 3; ++c)
        sacc[nb] = __builtin_amdgcn_mfma_f32_16x16x32_bf16(qf[c], *(const bf16x8*)(kbase + c * 32),
                                                           sacc[nb], 0, 0, 0);
    }
    float mnew[4], fac[4];
#pragma unroll
    for (int r = 0; r < 4; ++r) {
      float rm = fmaxf(fmaxf(sacc[0][r], sacc[1][r]), fmaxf(sacc[2][r], sacc[3][r]));
#pragma unroll
      for (int off = 1; off < 16; off <<= 1) rm = fmaxf(rm, __shfl_xor(rm, off, 64));
      rm *= SCALE;
      mnew[r] = fmaxf(mrow[r], rm);
      fac[r] = exp2f((mrow[r] - mnew[r]) * LOG2E);
      mrow[r] = mnew[r];
    }
    float pv[4][4];
#pragma unroll
    for (int nb = 0; nb < 4; ++nb)
#pragma unroll
      for (int r = 0; r < 4; ++r)
        pv[nb][r] = exp2f((sacc[nb][r] * SCALE - mnew[r]) * LOG2E);
#pragma unroll
    for (int r = 0; r < 4; ++r) {
      float sum = (pv[0][r] + pv[1][r]) + (pv[2][r] + pv[3][r]);
#pragma unroll
      for (int off = 1; off < 16; off <<= 1) sum += __shfl_xor(sum, off, 64);
      lrow[r] = lrow[r] * fac[r] + sum;
    }
#pragma unroll
    for (int nb5 = 0; nb5 < 5; ++nb5)
#pragma unroll
      for (int r = 0; r < 4; ++r) oacc[nb5][r] *= fac[r];
#pragma unroll
    for (int nb = 0; nb < 4; ++nb)
#pragma unroll
      for (int r = 0; r < 4; ++r)
        P_lds[(kg * 4 + r) * 64 + nb * 16 + row16] = f2bf(pv[nb][r]);
    asm volatile("s_waitcnt lgkmcnt(0)" ::: "memory");
    const bf16x8 pf0 = *(const bf16x8*)&P_lds[row16 * 64 + kg * 8];
    const bf16x8 pf1 = *(const bf16x8*)&P_lds[row16 * 64 + 32 + kg * 8];
#pragma unroll
    for (int nb5 = 0; nb5 < 5; ++nb5) {
      const unsigned short* vb = &Vt[((size_t)h * HD + nb5 * 16 + row16) * SEQ + s0 + kg * 8];
      oacc[nb5] = __builtin_amdgcn_mfma_f32_16x16x32_bf16(pf0, *(const bf16x8*)vb, oacc[nb5], 0, 0, 0);
      oacc[nb5] =
          __builtin_amdgcn_mfma_f32_16x16x32_bf16(pf1, *(const bf16x8*)(vb + 32), oacc[nb5], 0, 0, 0);
    }
  }
#pragma unroll
  for (int nb5 = 0; nb5 < 5; ++nb5)
#pragma unroll
    for (int r = 0; r < 4; ++r) {
      const int row = q0 + kg * 4 + r;
      Ob[(size_t)row * DIM + h * HD + nb5 * 16 + row16] = f2bf(oacc[nb5][r] / lrow[r]);
    }
}

// ---------------- host ----------------
extern "C" void kernel_launch(void* const* d_in, const int* in_sizes, int n_in, void* d_out,
                              int out_size, void* d_ws, size_t ws_size, hipStream_t stream) {
  (void)in_sizes; (void)n_in; (void)out_size; (void)ws_size;
  const float* hidden = (const float*)d_in[0];
  const float* rope = (const float*)d_in[2];
  const float* qkv_w = (const float*)d_in[3];
  const float* qkv_b = (const float*)d_in[4];
  const float* proj_w = (const float*)d_in[5];
  const float* proj_b = (const float*)d_in[6];

  char* p = (char*)d_ws;
  unsigned short* Xb = (unsigned short*)p;       p += (size_t)SEQ * DIM * 2;        // 10.5MB
  unsigned short* Wq = (unsigned short*)p;       p += (size_t)TDIM * DIM * 2;       // 9.8MB
  unsigned short* Wp = (unsigned short*)p;       p += (size_t)DIM * DIM * 2;        // 3.3MB
  float* ct = (float*)p;                         p += (size_t)SEQ * HD * 4;         // 1.3MB
  float* st = (float*)p;                         p += (size_t)SEQ * HD * 4;         // 1.3MB
  unsigned short* Y = (unsigned short*)p;        p += (size_t)SEQ * TDIM * 2;       // 31.5MB
  unsigned short* Qr = (unsigned short*)p;       p += (size_t)NH * SEQ * HDP * 2;   // 12.6MB
  unsigned short* Kr = (unsigned short*)p;       p += (size_t)NH * SEQ * HDP * 2;   // 12.6MB
  unsigned short* Vt = (unsigned short*)p;       p += (size_t)NH * HD * SEQ * 2;    // 10.5MB
  unsigned short* Ob = (unsigned short*)p;       p += (size_t)SEQ * DIM * 2;        // 10.5MB

  // 1) converts
  {
    int n4 = SEQ * DIM / 4;
    cvt_bf16<<<(n4 + 255) / 256, 256, 0, stream>>>(hidden, Xb, n4);
  }
  {
    int n4 = TDIM * DIM / 4;
    cvt_bf16<<<(n4 + 255) / 256, 256, 0, stream>>>(qkv_w, Wq, n4);
  }
  {
    int n4 = DIM * DIM / 4;
    cvt_bf16<<<(n4 + 255) / 256, 256, 0, stream>>>(proj_w, Wp, n4);
  }
  // 2) cos/sin table
  {
    int n = SEQ * HD;
    trig_tab<<<(n + 255) / 256, 256, 0, stream>>>(rope, ct, st, n);
  }
  // 3) QKV GEMM (bf16 out, fused bias)
  gemm_bt<0><<<dim3(TDIM / 128, SEQ / 128), 256, 0, stream>>>(Xb, Wq, qkv_b, Y, SEQ, TDIM, DIM);
  // 4) RoPE + repack
  rope_qk<<<dim3(NH, SEQ), 128, 0, stream>>>(Y, ct, st, Qr, Kr);
  vtrans<<<NH * HD, 256, 0, stream>>>(Y, Vt);
  // 5) attention
  attn<<<dim3(SEQ / 16, NH), 64, 0, stream>>>(Qr, Kr, Vt, Ob);
  // 6) out-proj (fp32 out, fused bias)
  gemm_bt<1><<<dim3(DIM / 128, SEQ / 128), 256, 0, stream>>>(Ob, Wp, proj_b, d_out, SEQ, DIM, DIM);
}

// Round 2
// 546.202 us; speedup vs baseline: 1.1982x; 1.1982x over previous
//
#include <hip/hip_runtime.h>

#define SEQ 4096
#define DIM 1280
#define NH 16
#define HD 80
#define HQ 96
#define TDIM 3840

// softmax scale (1/sqrt(80)) * log2(e), folded into Q at repack
#define QSC 0.16129842980505168f

typedef __bf16 bf16x8 __attribute__((ext_vector_type(8)));
typedef __bf16 bf16x4 __attribute__((ext_vector_type(4)));
typedef float f32x4 __attribute__((ext_vector_type(4)));

__device__ __forceinline__ unsigned short f2bf(float f) {
  unsigned int u = __builtin_bit_cast(unsigned int, f);
  u += 0x7FFF + ((u >> 16) & 1);
  return (unsigned short)(u >> 16);
}
__device__ __forceinline__ float bf2f(unsigned short b) {
  unsigned int u = ((unsigned int)b) << 16;
  return __builtin_bit_cast(float, u);
}
__device__ __forceinline__ unsigned int cvtpk(float a, float b) {
  unsigned int r;
  asm("v_cvt_pk_bf16_f32 %0, %1, %2" : "=v"(r) : "v"(a), "v"(b));
  return r;
}

__device__ __forceinline__ void gload_lds16(const void* g, void* l) {
  __builtin_amdgcn_global_load_lds(
      (const __attribute__((address_space(1))) unsigned int*)g,
      (__attribute__((address_space(3))) unsigned int*)l, 16, 0, 0);
}

// ---------------- fp32 -> bf16 convert (vectorized) ----------------
__global__ void cvt_bf16(const float* __restrict__ in, unsigned short* __restrict__ out, int n4) {
  int i = blockIdx.x * 256 + threadIdx.x;
  if (i >= n4) return;
  float4 f = ((const float4*)in)[i];
  ushort4 o;
  o.x = f2bf(f.x); o.y = f2bf(f.y); o.z = f2bf(f.z); o.w = f2bf(f.w);
  ((ushort4*)out)[i] = o;
}

// ---------------- cos/sin table ----------------
__global__ void trig_tab(const float* __restrict__ rope, float* __restrict__ ct,
                         float* __restrict__ st, int n) {
  int i = blockIdx.x * 256 + threadIdx.x;
  if (i >= n) return;
  float v = rope[i];
  ct[i] = cosf(v);
  st[i] = sinf(v);
}

// ---------------- GEMM: C = A(MxK) @ B(NxK)^T + bias ----------------
template <int F32OUT>
__global__ __launch_bounds__(256) void gemm_bt(const unsigned short* __restrict__ A,
                                               const unsigned short* __restrict__ B,
                                               const float* __restrict__ bias,
                                               void* __restrict__ Cout, int M, int N, int K) {
  __shared__ unsigned short As[4096];
  __shared__ unsigned short Bs[4096];
  const int t = threadIdx.x;
  const int l = t & 63, w = t >> 6;
  const int row16 = l & 15, kg = l >> 4;
  const int brow = blockIdx.y * 128, bcol = blockIdx.x * 128;
  const int wr = w >> 1, wc = w & 1;
  f32x4 acc[4][4] = {};
  const size_t Ks = (size_t)K;
  const unsigned short* Ag = A + (brow + (t >> 2)) * Ks + (t & 3) * 8;
  const unsigned short* Bg = B + (bcol + (t >> 2)) * Ks + (t & 3) * 8;
  unsigned short* AsW = As + w * 512;
  unsigned short* BsW = Bs + w * 512;
  const int nk = K >> 5;
  for (int kt = 0; kt < nk; ++kt) {
    const unsigned short* a = Ag + kt * 32;
    const unsigned short* b = Bg + kt * 32;
    gload_lds16(a, AsW);
    gload_lds16(a + 64 * Ks, AsW + 2048);
    gload_lds16(b, BsW);
    gload_lds16(b + 64 * Ks, BsW + 2048);
    __syncthreads();
    bf16x8 af[4], bfr[4];
#pragma unroll
    for (int m = 0; m < 4; ++m)
      af[m] = *(const bf16x8*)&As[(wr * 64 + m * 16 + row16) * 32 + kg * 8];
#pragma unroll
    for (int n = 0; n < 4; ++n)
      bfr[n] = *(const bf16x8*)&Bs[(wc * 64 + n * 16 + row16) * 32 + kg * 8];
#pragma unroll
    for (int m = 0; m < 4; ++m)
#pragma unroll
      for (int n = 0; n < 4; ++n)
        acc[m][n] = __builtin_amdgcn_mfma_f32_16x16x32_bf16(af[m], bfr[n], acc[m][n], 0, 0, 0);
    __syncthreads();
  }
#pragma unroll
  for (int n = 0; n < 4; ++n) {
    const int col = bcol + wc * 64 + n * 16 + row16;
    const float bv = bias[col];
#pragma unroll
    for (int m = 0; m < 4; ++m) {
      const int row = brow + wr * 64 + m * 16 + kg * 4;
#pragma unroll
      for (int r = 0; r < 4; ++r) {
        float v = acc[m][n][r] + bv;
        if (F32OUT)
          ((float*)Cout)[(size_t)(row + r) * N + col] = v;
        else
          ((unsigned short*)Cout)[(size_t)(row + r) * N + col] = f2bf(v);
      }
    }
  }
}

// ---------------- RoPE + repack Q,K -> [h][s][96]; Q pre-scaled ----------------
__global__ void rope_qk(const unsigned short* __restrict__ Y, const float* __restrict__ ct,
                        const float* __restrict__ st, unsigned short* __restrict__ Qr,
                        unsigned short* __restrict__ Kr) {
  const int h = blockIdx.x;
  const int s = blockIdx.y;
  const int d = threadIdx.x;
  if (d >= HQ) return;
  const size_t orow = ((size_t)h * SEQ + s) * HQ + d;
  if (d >= HD) {
    Qr[orow] = 0;
    Kr[orow] = 0;
    return;
  }
  const int dp = d < 40 ? d + 40 : d - 40;
  const float sign = d < 40 ? -1.f : 1.f;
  const unsigned short* yrow = Y + (size_t)s * TDIM;
  const float c = ct[s * HD + d];
  const float sn = st[s * HD + d];
  const float q = bf2f(yrow[h * HD + d]);
  const float qp = bf2f(yrow[h * HD + dp]);
  const float k = bf2f(yrow[DIM + h * HD + d]);
  const float kp = bf2f(yrow[DIM + h * HD + dp]);
  Qr[orow] = f2bf((q * c + sign * qp * sn) * QSC);
  Kr[orow] = f2bf(k * c + sign * kp * sn);
}

// ---------------- V transpose -> [h][d=80][s] ----------------
__global__ void vtrans(const unsigned short* __restrict__ Y, unsigned short* __restrict__ Vt) {
  const int hd = blockIdx.x;  // 0..1279
  const int h = hd / HD, d = hd % HD;
  const size_t src_col = 2 * DIM + (size_t)h * HD + d;
  for (int s = threadIdx.x; s < SEQ; s += 256)
    Vt[(size_t)hd * SEQ + s] = Y[(size_t)s * TDIM + src_col];
}

// ---------------- Flash attention v2: swapped operands, register softmax ----------------
// 1 wave/block, 32 q-rows/wave, K-tiles of 64. grid.x = (SEQ/32)*NH, h = bid&15 (XCD affinity)
__global__ __launch_bounds__(64) void attn2(const unsigned short* __restrict__ Qr,
                                            const unsigned short* __restrict__ Kr,
                                            const unsigned short* __restrict__ Vt,
                                            unsigned short* __restrict__ Ob) {
  const int l = threadIdx.x;
  const int row16 = l & 15, kg = l >> 4;
  const int bid = blockIdx.x;
  const int h = bid & 15;            // head -> XCD = h&7 (L2 affinity)
  const int q0 = (bid >> 4) * 32;
  const size_t hs = (size_t)h * SEQ;

  const unsigned short* Qh = Qr + hs * HQ;
  const unsigned short* Kh = Kr + hs * HQ;
  const unsigned short* Vh = Vt + (size_t)h * HD * SEQ;

  // Q fragments (B-operand of swapped QK^T): q = q0 + qb*16 + row16
  bf16x8 qf[2][3];
#pragma unroll
  for (int qb = 0; qb < 2; ++qb)
#pragma unroll
    for (int c = 0; c < 3; ++c)
      qf[qb][c] = *(const bf16x8*)&Qh[(size_t)(q0 + qb * 16 + row16) * HQ + c * 32 + kg * 8];

  union { bf16x8 v; unsigned int u[4]; } ones;
  ones.u[0] = ones.u[1] = ones.u[2] = ones.u[3] = 0x3F803F80u;

  float m_run[2] = {-3.0e38f, -3.0e38f};
  f32x4 oacc[2][6] = {};  // [qb][d-block 0..4, 5 = row-sum l]

  const unsigned short* Kp = Kh + row16 * HQ + kg * 8;
  const unsigned short* Vp = Vh + (size_t)row16 * SEQ + kg * 4;

#pragma unroll 1
  for (int s0 = 0; s0 < SEQ; s0 += 64) {
    // ---- K loads (A-operand rows = keys) ----
    bf16x8 kf[4][3];
#pragma unroll
    for (int nb = 0; nb < 4; ++nb)
#pragma unroll
      for (int c = 0; c < 3; ++c)
        kf[nb][c] = *(const bf16x8*)&Kp[(size_t)(s0 + nb * 16) * HQ + c * 32];
    // ---- S^T = K · Q^T : lane holds 16 scores for q=row16 (per qb) ----
    f32x4 sacc[2][4] = {};
#pragma unroll
    for (int c = 0; c < 3; ++c)
#pragma unroll
      for (int qb = 0; qb < 2; ++qb)
#pragma unroll
        for (int nb = 0; nb < 4; ++nb)
          sacc[qb][nb] =
              __builtin_amdgcn_mfma_f32_16x16x32_bf16(kf[nb][c], qf[qb][c], sacc[qb][nb], 0, 0, 0);
    // ---- V loads early (latency hidden under softmax); permuted k-map:
    // A-frag slot j of lane kg <-> s_local = ks*32 + (j>>2)*16 + kg*4 + (j&3)
    union { bf16x8 v8; bf16x4 h4[2]; } vf[5][2];
#pragma unroll
    for (int n5 = 0; n5 < 5; ++n5)
#pragma unroll
      for (int ks = 0; ks < 2; ++ks) {
        vf[n5][ks].h4[0] = *(const bf16x4*)&Vp[(size_t)n5 * 16 * SEQ + s0 + ks * 32];
        vf[n5][ks].h4[1] = *(const bf16x4*)&Vp[(size_t)n5 * 16 * SEQ + s0 + ks * 32 + 16];
      }
    // ---- per-lane softmax (q = row16), cross-lane only over kg (2 shfls) ----
    float pmax[2];
#pragma unroll
    for (int qb = 0; qb < 2; ++qb) {
      float a0 = fmaxf(fmaxf(sacc[qb][0][0], sacc[qb][0][1]), fmaxf(sacc[qb][0][2], sacc[qb][0][3]));
      float a1 = fmaxf(fmaxf(sacc[qb][1][0], sacc[qb][1][1]), fmaxf(sacc[qb][1][2], sacc[qb][1][3]));
      float a2 = fmaxf(fmaxf(sacc[qb][2][0], sacc[qb][2][1]), fmaxf(sacc[qb][2][2], sacc[qb][2][3]));
      float a3 = fmaxf(fmaxf(sacc[qb][3][0], sacc[qb][3][1]), fmaxf(sacc[qb][3][2], sacc[qb][3][3]));
      float m0 = fmaxf(fmaxf(a0, a1), fmaxf(a2, a3));
      m0 = fmaxf(m0, __shfl_xor(m0, 16, 64));
      m0 = fmaxf(m0, __shfl_xor(m0, 32, 64));
      pmax[qb] = m0;
    }
    // defer-max (T13): only rescale when max grew by > 8 (log2 units)
    if (!__all((pmax[0] - m_run[0] <= 8.0f) & (pmax[1] - m_run[1] <= 8.0f))) {
#pragma unroll
      for (int qb = 0; qb < 2; ++qb) {
        float mn = fmaxf(m_run[qb], pmax[qb]);
        float fac = exp2f(m_run[qb] - mn);
        m_run[qb] = mn;
#pragma unroll
        for (int n6 = 0; n6 < 6; ++n6)
#pragma unroll
          for (int r = 0; r < 4; ++r) oacc[qb][n6][r] *= fac;
      }
    }
    // P = exp2(S - m) in place
#pragma unroll
    for (int qb = 0; qb < 2; ++qb)
#pragma unroll
      for (int nb = 0; nb < 4; ++nb)
#pragma unroll
        for (int r = 0; r < 4; ++r) sacc[qb][nb][r] = exp2f(sacc[qb][nb][r] - m_run[qb]);
    // pack P -> bf16 B-fragments (same permuted k-map as V) and PV + row-sum
#pragma unroll
    for (int qb = 0; qb < 2; ++qb)
#pragma unroll
      for (int ks = 0; ks < 2; ++ks) {
        union { bf16x8 v; unsigned int u[4]; } pf;
        pf.u[0] = cvtpk(sacc[qb][2 * ks][0], sacc[qb][2 * ks][1]);
        pf.u[1] = cvtpk(sacc[qb][2 * ks][2], sacc[qb][2 * ks][3]);
        pf.u[2] = cvtpk(sacc[qb][2 * ks + 1][0], sacc[qb][2 * ks + 1][1]);
        pf.u[3] = cvtpk(sacc[qb][2 * ks + 1][2], sacc[qb][2 * ks + 1][3]);
#pragma unroll
        for (int n5 = 0; n5 < 5; ++n5)
          oacc[qb][n5] =
              __builtin_amdgcn_mfma_f32_16x16x32_bf16(vf[n5][ks].v8, pf.v, oacc[qb][n5], 0, 0, 0);
        oacc[qb][5] = __builtin_amdgcn_mfma_f32_16x16x32_bf16(ones.v, pf.v, oacc[qb][5], 0, 0, 0);
      }
  }
  // ---- epilogue: O^T lane layout: d = n5*16 + kg*4 + r, q = q0 + qb*16 + row16 ----
#pragma unroll
  for (int qb = 0; qb < 2; ++qb) {
    float rl = 1.0f / oacc[qb][5][0];
    unsigned short* orow = Ob + (size_t)(q0 + qb * 16 + row16) * DIM + h * HD + kg * 4;
#pragma unroll
    for (int n5 = 0; n5 < 5; ++n5) {
      ushort4 o;
      o.x = f2bf(oacc[qb][n5][0] * rl);
      o.y = f2bf(oacc[qb][n5][1] * rl);
      o.z = f2bf(oacc[qb][n5][2] * rl);
      o.w = f2bf(oacc[qb][n5][3] * rl);
      *(ushort4*)(orow + n5 * 16) = o;
    }
  }
}

// ---------------- host ----------------
extern "C" void kernel_launch(void* const* d_in, const int* in_sizes, int n_in, void* d_out,
                              int out_size, void* d_ws, size_t ws_size, hipStream_t stream) {
  (void)in_sizes; (void)n_in; (void)out_size; (void)ws_size;
  const float* hidden = (const float*)d_in[0];
  const float* rope = (const float*)d_in[2];
  const float* qkv_w = (const float*)d_in[3];
  const float* qkv_b = (const float*)d_in[4];
  const float* proj_w = (const float*)d_in[5];
  const float* proj_b = (const float*)d_in[6];

  char* p = (char*)d_ws;
  unsigned short* Xb = (unsigned short*)p;       p += (size_t)SEQ * DIM * 2;
  unsigned short* Wq = (unsigned short*)p;       p += (size_t)TDIM * DIM * 2;
  unsigned short* Wp = (unsigned short*)p;       p += (size_t)DIM * DIM * 2;
  float* ct = (float*)p;                         p += (size_t)SEQ * HD * 4;
  float* st = (float*)p;                         p += (size_t)SEQ * HD * 4;
  unsigned short* Y = (unsigned short*)p;        p += (size_t)SEQ * TDIM * 2;
  unsigned short* Qr = (unsigned short*)p;       p += (size_t)NH * SEQ * HQ * 2;
  unsigned short* Kr = (unsigned short*)p;       p += (size_t)NH * SEQ * HQ * 2;
  unsigned short* Vt = (unsigned short*)p;       p += (size_t)NH * HD * SEQ * 2;
  unsigned short* Ob = (unsigned short*)p;       p += (size_t)SEQ * DIM * 2;

  {
    int n4 = SEQ * DIM / 4;
    cvt_bf16<<<(n4 + 255) / 256, 256, 0, stream>>>(hidden, Xb, n4);
  }
  {
    int n4 = TDIM * DIM / 4;
    cvt_bf16<<<(n4 + 255) / 256, 256, 0, stream>>>(qkv_w, Wq, n4);
  }
  {
    int n4 = DIM * DIM / 4;
    cvt_bf16<<<(n4 + 255) / 256, 256, 0, stream>>>(proj_w, Wp, n4);
  }
  {
    int n = SEQ * HD;
    trig_tab<<<(n + 255) / 256, 256, 0, stream>>>(rope, ct, st, n);
  }
  gemm_bt<0><<<dim3(TDIM / 128, SEQ / 128), 256, 0, stream>>>(Xb, Wq, qkv_b, Y, SEQ, TDIM, DIM);
  rope_qk<<<dim3(NH, SEQ), 128, 0, stream>>>(Y, ct, st, Qr, Kr);
  vtrans<<<NH * HD, 256, 0, stream>>>(Y, Vt);
  attn2<<<(SEQ / 32) * NH, 64, 0, stream>>>(Qr, Kr, Vt, Ob);
  gemm_bt<1><<<dim3(DIM / 128, SEQ / 128), 256, 0, stream>>>(Ob, Wp, proj_b, d_out, SEQ, DIM, DIM);
}

// Round 3
// 320.606 us; speedup vs baseline: 2.0413x; 1.7037x over previous
//
#include <hip/hip_runtime.h>

#define SEQ 4096
#define DIM 1280
#define NH 16
#define HD 80
#define HQ 96
#define TDIM 3840

// softmax scale (1/sqrt(80)) * log2(e), folded into Q at repack
#define QSC 0.16129842980505168f

typedef __bf16 bf16x8 __attribute__((ext_vector_type(8)));
typedef __bf16 bf16x4 __attribute__((ext_vector_type(4)));
typedef float f32x4 __attribute__((ext_vector_type(4)));

__device__ __forceinline__ unsigned short f2bf(float f) {
  unsigned int u = __builtin_bit_cast(unsigned int, f);
  u += 0x7FFF + ((u >> 16) & 1);
  return (unsigned short)(u >> 16);
}
__device__ __forceinline__ float bf2f(unsigned short b) {
  unsigned int u = ((unsigned int)b) << 16;
  return __builtin_bit_cast(float, u);
}
__device__ __forceinline__ unsigned int cvtpk(float a, float b) {
  unsigned int r;
  asm("v_cvt_pk_bf16_f32 %0, %1, %2" : "=v"(r) : "v"(a), "v"(b));
  return r;
}

__device__ __forceinline__ void gload_lds16(const void* g, void* l) {
  __builtin_amdgcn_global_load_lds(
      (const __attribute__((address_space(1))) unsigned int*)g,
      (__attribute__((address_space(3))) unsigned int*)l, 16, 0, 0);
}

// ---------------- fp32 -> bf16 convert (vectorized) ----------------
__global__ void cvt_bf16(const float* __restrict__ in, unsigned short* __restrict__ out, int n4) {
  int i = blockIdx.x * 256 + threadIdx.x;
  if (i >= n4) return;
  float4 f = ((const float4*)in)[i];
  ushort4 o;
  o.x = f2bf(f.x); o.y = f2bf(f.y); o.z = f2bf(f.z); o.w = f2bf(f.w);
  ((ushort4*)out)[i] = o;
}

// ---------------- cos/sin table ----------------
__global__ void trig_tab(const float* __restrict__ rope, float* __restrict__ ct,
                         float* __restrict__ st, int n) {
  int i = blockIdx.x * 256 + threadIdx.x;
  if (i >= n) return;
  float v = rope[i];
  ct[i] = cosf(v);
  st[i] = sinf(v);
}

// ---------------- GEMM: C = A(MxK) @ B(NxK)^T + bias ----------------
template <int F32OUT>
__global__ __launch_bounds__(256) void gemm_bt(const unsigned short* __restrict__ A,
                                               const unsigned short* __restrict__ B,
                                               const float* __restrict__ bias,
                                               void* __restrict__ Cout, int M, int N, int K) {
  __shared__ unsigned short As[4096];
  __shared__ unsigned short Bs[4096];
  const int t = threadIdx.x;
  const int l = t & 63, w = t >> 6;
  const int row16 = l & 15, kg = l >> 4;
  const int brow = blockIdx.y * 128, bcol = blockIdx.x * 128;
  const int wr = w >> 1, wc = w & 1;
  f32x4 acc[4][4] = {};
  const size_t Ks = (size_t)K;
  const unsigned short* Ag = A + (brow + (t >> 2)) * Ks + (t & 3) * 8;
  const unsigned short* Bg = B + (bcol + (t >> 2)) * Ks + (t & 3) * 8;
  unsigned short* AsW = As + w * 512;
  unsigned short* BsW = Bs + w * 512;
  const int nk = K >> 5;
  for (int kt = 0; kt < nk; ++kt) {
    const unsigned short* a = Ag + kt * 32;
    const unsigned short* b = Bg + kt * 32;
    gload_lds16(a, AsW);
    gload_lds16(a + 64 * Ks, AsW + 2048);
    gload_lds16(b, BsW);
    gload_lds16(b + 64 * Ks, BsW + 2048);
    __syncthreads();
    bf16x8 af[4], bfr[4];
#pragma unroll
    for (int m = 0; m < 4; ++m)
      af[m] = *(const bf16x8*)&As[(wr * 64 + m * 16 + row16) * 32 + kg * 8];
#pragma unroll
    for (int n = 0; n < 4; ++n)
      bfr[n] = *(const bf16x8*)&Bs[(wc * 64 + n * 16 + row16) * 32 + kg * 8];
#pragma unroll
    for (int m = 0; m < 4; ++m)
#pragma unroll
      for (int n = 0; n < 4; ++n)
        acc[m][n] = __builtin_amdgcn_mfma_f32_16x16x32_bf16(af[m], bfr[n], acc[m][n], 0, 0, 0);
    __syncthreads();
  }
#pragma unroll
  for (int n = 0; n < 4; ++n) {
    const int col = bcol + wc * 64 + n * 16 + row16;
    const float bv = bias[col];
#pragma unroll
    for (int m = 0; m < 4; ++m) {
      const int row = brow + wr * 64 + m * 16 + kg * 4;
#pragma unroll
      for (int r = 0; r < 4; ++r) {
        float v = acc[m][n][r] + bv;
        if (F32OUT)
          ((float*)Cout)[(size_t)(row + r) * N + col] = v;
        else
          ((unsigned short*)Cout)[(size_t)(row + r) * N + col] = f2bf(v);
      }
    }
  }
}

// ---------------- RoPE + repack Q,K -> [h][s][96]; Q pre-scaled ----------------
__global__ void rope_qk(const unsigned short* __restrict__ Y, const float* __restrict__ ct,
                        const float* __restrict__ st, unsigned short* __restrict__ Qr,
                        unsigned short* __restrict__ Kr) {
  const int h = blockIdx.x;
  const int s = blockIdx.y;
  const int d = threadIdx.x;
  if (d >= HQ) return;
  const size_t orow = ((size_t)h * SEQ + s) * HQ + d;
  if (d >= HD) {
    Qr[orow] = 0;
    Kr[orow] = 0;
    return;
  }
  const int dp = d < 40 ? d + 40 : d - 40;
  const float sign = d < 40 ? -1.f : 1.f;
  const unsigned short* yrow = Y + (size_t)s * TDIM;
  const float c = ct[s * HD + d];
  const float sn = st[s * HD + d];
  const float q = bf2f(yrow[h * HD + d]);
  const float qp = bf2f(yrow[h * HD + dp]);
  const float k = bf2f(yrow[DIM + h * HD + d]);
  const float kp = bf2f(yrow[DIM + h * HD + dp]);
  Qr[orow] = f2bf((q * c + sign * qp * sn) * QSC);
  Kr[orow] = f2bf(k * c + sign * kp * sn);
}

// ---------------- V transpose -> [h][d=80][s] ----------------
__global__ void vtrans(const unsigned short* __restrict__ Y, unsigned short* __restrict__ Vt) {
  const int hd = blockIdx.x;  // 0..1279
  const int h = hd / HD, d = hd % HD;
  const size_t src_col = 2 * DIM + (size_t)h * HD + d;
  for (int s = threadIdx.x; s < SEQ; s += 256)
    Vt[(size_t)hd * SEQ + s] = Y[(size_t)s * TDIM + src_col];
}

// ---------------- Flash attention v3: 4-wave blocks, double-buffered LDS staging ----
// Block covers 128 q-rows of one head; each wave owns 32. grid (SEQ/128, NH).
// K LDS rows padded to 256B, XOR-swizzled on 16B granules (slot ^= row&7);
// V LDS rows 128B, same swizzle. Linear gload_lds dest + inverse-swizzled source.
__global__ __launch_bounds__(256, 2) void attn3(const unsigned short* __restrict__ Qr,
                                                const unsigned short* __restrict__ Kr,
                                                const unsigned short* __restrict__ Vt,
                                                unsigned short* __restrict__ Ob) {
  constexpr int KROWB = 256;
  constexpr int KBYT = 64 * KROWB;   // 16384
  constexpr int VBYT = 80 * 128;     // 10240
  constexpr int BUFB = KBYT + VBYT;  // 26624
  __shared__ char smem[2 * BUFB];

  const int tid = threadIdx.x;
  const int l = tid & 63, w = tid >> 6;
  const int row16 = l & 15, kg = l >> 4;
  const int h = blockIdx.y;
  const int q0 = blockIdx.x * 128 + w * 32;
  const size_t hs = (size_t)h * SEQ;

  const unsigned short* Qh = Qr + hs * HQ;
  const char* Kh = (const char*)(Kr + hs * HQ);
  const char* Vh = (const char*)(Vt + (size_t)h * HD * SEQ);

  // ---- staging lane constants: 16 K-chunks + 10 V-chunks of 1KB, chunk cid = w + 4*i
  const int nst = (w < 2) ? 7 : 6;
  unsigned soff[7], sdst[7];
#pragma unroll
  for (int i = 0; i < 7; ++i) {
    const int cid = w + 4 * i;
    if (i < 4) {  // K chunk: 4 rows of 256B each
      const int r = (cid << 2) + (l >> 4);
      const int cb = (l & 15) << 4;
      soff[i] = r * 192 + (cb ^ ((r & 7) << 4));  // global K row stride = 192B
      sdst[i] = cid << 10;
    } else if (cid - 16 < 10) {  // V chunk: 8 rows of 128B each
      const int j = cid - 16;
      const int d = (j << 3) + (l >> 3);
      const int sb = (l & 7) << 4;
      soff[i] = d * 8192 + (sb ^ ((d & 7) << 4));  // global V row stride = 8192B
      sdst[i] = KBYT + (j << 10);
    }
  }

  // ---- LDS read base addresses (tile-invariant) ----
  const int swl = (row16 & 7) << 4;
  int kb_[3];
#pragma unroll
  for (int c = 0; c < 3; ++c) kb_[c] = row16 * 256 + ((c * 64 + kg * 16) ^ swl);
  int vb_[2][2];
#pragma unroll
  for (int ks = 0; ks < 2; ++ks)
#pragma unroll
    for (int h2 = 0; h2 < 2; ++h2)
      vb_[ks][h2] = KBYT + row16 * 128 + ((kg * 8 + ks * 64 + h2 * 32) ^ swl);

  auto STAGE = [&](int t, int bb) {
    const char* ks = Kh + (size_t)t * (64 * 192);
    const char* vs = Vh + (size_t)t * 128;
#pragma unroll
    for (int i = 0; i < 4; ++i) gload_lds16(ks + soff[i], smem + bb + sdst[i]);
#pragma unroll
    for (int i = 4; i < 7; ++i)
      if (i < nst) gload_lds16(vs + soff[i], smem + bb + sdst[i]);
  };

  // ---- Q fragments (B-operand of swapped QK^T) ----
  bf16x8 qf[2][3];
#pragma unroll
  for (int qb = 0; qb < 2; ++qb)
#pragma unroll
    for (int c = 0; c < 3; ++c)
      qf[qb][c] = *(const bf16x8*)&Qh[(size_t)(q0 + qb * 16 + row16) * HQ + c * 32 + kg * 8];

  union { bf16x8 v; unsigned int u[4]; } ones;
  ones.u[0] = ones.u[1] = ones.u[2] = ones.u[3] = 0x3F803F80u;

  float m_run[2] = {-3.0e38f, -3.0e38f};
  f32x4 oacc[2][6] = {};  // [qb][d-block 0..4, 5 = row-sum l]

  STAGE(0, 0);
  __syncthreads();

#pragma unroll 1
  for (int t = 0; t < SEQ / 64; ++t) {
    const int cur = t & 1;
    if (t + 1 < SEQ / 64) STAGE(t + 1, (cur ^ 1) * BUFB);
    const char* B = smem + cur * BUFB;
    // ---- K fragments from LDS ----
    bf16x8 kf[4][3];
#pragma unroll
    for (int nb = 0; nb < 4; ++nb)
#pragma unroll
      for (int c = 0; c < 3; ++c) kf[nb][c] = *(const bf16x8*)(B + kb_[c] + nb * 4096);
    // ---- S^T = K · Q^T ----
    f32x4 sacc[2][4] = {};
    __builtin_amdgcn_s_setprio(1);
#pragma unroll
    for (int c = 0; c < 3; ++c)
#pragma unroll
      for (int qb = 0; qb < 2; ++qb)
#pragma unroll
        for (int nb = 0; nb < 4; ++nb)
          sacc[qb][nb] =
              __builtin_amdgcn_mfma_f32_16x16x32_bf16(kf[nb][c], qf[qb][c], sacc[qb][nb], 0, 0, 0);
    __builtin_amdgcn_s_setprio(0);
    // ---- V fragments from LDS (permuted k-map: slot j of lane kg <-> s_local =
    //      ks*32 + (j>>2)*16 + kg*4 + (j&3)) ----
    union { bf16x8 v8; bf16x4 h4[2]; } vf[5][2];
#pragma unroll
    for (int n5 = 0; n5 < 5; ++n5)
#pragma unroll
      for (int ks = 0; ks < 2; ++ks) {
        vf[n5][ks].h4[0] = *(const bf16x4*)(B + vb_[ks][0] + n5 * 2048);
        vf[n5][ks].h4[1] = *(const bf16x4*)(B + vb_[ks][1] + n5 * 2048);
      }
    // ---- per-lane softmax (q = row16), cross-lane only over kg ----
    float pmax[2];
#pragma unroll
    for (int qb = 0; qb < 2; ++qb) {
      float a0 = fmaxf(fmaxf(sacc[qb][0][0], sacc[qb][0][1]), fmaxf(sacc[qb][0][2], sacc[qb][0][3]));
      float a1 = fmaxf(fmaxf(sacc[qb][1][0], sacc[qb][1][1]), fmaxf(sacc[qb][1][2], sacc[qb][1][3]));
      float a2 = fmaxf(fmaxf(sacc[qb][2][0], sacc[qb][2][1]), fmaxf(sacc[qb][2][2], sacc[qb][2][3]));
      float a3 = fmaxf(fmaxf(sacc[qb][3][0], sacc[qb][3][1]), fmaxf(sacc[qb][3][2], sacc[qb][3][3]));
      float m0 = fmaxf(fmaxf(a0, a1), fmaxf(a2, a3));
      m0 = fmaxf(m0, __shfl_xor(m0, 16, 64));
      m0 = fmaxf(m0, __shfl_xor(m0, 32, 64));
      pmax[qb] = m0;
    }
    if (!__all((pmax[0] - m_run[0] <= 8.0f) & (pmax[1] - m_run[1] <= 8.0f))) {
#pragma unroll
      for (int qb = 0; qb < 2; ++qb) {
        float mn = fmaxf(m_run[qb], pmax[qb]);
        float fac = exp2f(m_run[qb] - mn);
        m_run[qb] = mn;
#pragma unroll
        for (int n6 = 0; n6 < 6; ++n6)
#pragma unroll
          for (int r = 0; r < 4; ++r) oacc[qb][n6][r] *= fac;
      }
    }
#pragma unroll
    for (int qb = 0; qb < 2; ++qb)
#pragma unroll
      for (int nb = 0; nb < 4; ++nb)
#pragma unroll
        for (int r = 0; r < 4; ++r) sacc[qb][nb][r] = exp2f(sacc[qb][nb][r] - m_run[qb]);
    // ---- pack P -> bf16 (same permuted k-map as V) and PV + row-sum ----
    __builtin_amdgcn_s_setprio(1);
#pragma unroll
    for (int qb = 0; qb < 2; ++qb)
#pragma unroll
      for (int ks = 0; ks < 2; ++ks) {
        union { bf16x8 v; unsigned int u[4]; } pf;
        pf.u[0] = cvtpk(sacc[qb][2 * ks][0], sacc[qb][2 * ks][1]);
        pf.u[1] = cvtpk(sacc[qb][2 * ks][2], sacc[qb][2 * ks][3]);
        pf.u[2] = cvtpk(sacc[qb][2 * ks + 1][0], sacc[qb][2 * ks + 1][1]);
        pf.u[3] = cvtpk(sacc[qb][2 * ks + 1][2], sacc[qb][2 * ks + 1][3]);
#pragma unroll
        for (int n5 = 0; n5 < 5; ++n5)
          oacc[qb][n5] =
              __builtin_amdgcn_mfma_f32_16x16x32_bf16(vf[n5][ks].v8, pf.v, oacc[qb][n5], 0, 0, 0);
        oacc[qb][5] = __builtin_amdgcn_mfma_f32_16x16x32_bf16(ones.v, pf.v, oacc[qb][5], 0, 0, 0);
      }
    __builtin_amdgcn_s_setprio(0);
    __syncthreads();
  }
  // ---- epilogue: d = n5*16 + kg*4 + r, q = q0 + qb*16 + row16 ----
#pragma unroll
  for (int qb = 0; qb < 2; ++qb) {
    float rl = 1.0f / oacc[qb][5][0];
    unsigned short* orow = Ob + (size_t)(q0 + qb * 16 + row16) * DIM + h * HD + kg * 4;
#pragma unroll
    for (int n5 = 0; n5 < 5; ++n5) {
      ushort4 o;
      o.x = f2bf(oacc[qb][n5][0] * rl);
      o.y = f2bf(oacc[qb][n5][1] * rl);
      o.z = f2bf(oacc[qb][n5][2] * rl);
      o.w = f2bf(oacc[qb][n5][3] * rl);
      *(ushort4*)(orow + n5 * 16) = o;
    }
  }
}

// ---------------- host ----------------
extern "C" void kernel_launch(void* const* d_in, const int* in_sizes, int n_in, void* d_out,
                              int out_size, void* d_ws, size_t ws_size, hipStream_t stream) {
  (void)in_sizes; (void)n_in; (void)out_size; (void)ws_size;
  const float* hidden = (const float*)d_in[0];
  const float* rope = (const float*)d_in[2];
  const float* qkv_w = (const float*)d_in[3];
  const float* qkv_b = (const float*)d_in[4];
  const float* proj_w = (const float*)d_in[5];
  const float* proj_b = (const float*)d_in[6];

  char* p = (char*)d_ws;
  unsigned short* Xb = (unsigned short*)p;       p += (size_t)SEQ * DIM * 2;
  unsigned short* Wq = (unsigned short*)p;       p += (size_t)TDIM * DIM * 2;
  unsigned short* Wp = (unsigned short*)p;       p += (size_t)DIM * DIM * 2;
  float* ct = (float*)p;                         p += (size_t)SEQ * HD * 4;
  float* st = (float*)p;                         p += (size_t)SEQ * HD * 4;
  unsigned short* Y = (unsigned short*)p;        p += (size_t)SEQ * TDIM * 2;
  unsigned short* Qr = (unsigned short*)p;       p += (size_t)NH * SEQ * HQ * 2;
  unsigned short* Kr = (unsigned short*)p;       p += (size_t)NH * SEQ * HQ * 2;
  unsigned short* Vt = (unsigned short*)p;       p += (size_t)NH * HD * SEQ * 2;
  unsigned short* Ob = (unsigned short*)p;       p += (size_t)SEQ * DIM * 2;

  {
    int n4 = SEQ * DIM / 4;
    cvt_bf16<<<(n4 + 255) / 256, 256, 0, stream>>>(hidden, Xb, n4);
  }
  {
    int n4 = TDIM * DIM / 4;
    cvt_bf16<<<(n4 + 255) / 256, 256, 0, stream>>>(qkv_w, Wq, n4);
  }
  {
    int n4 = DIM * DIM / 4;
    cvt_bf16<<<(n4 + 255) / 256, 256, 0, stream>>>(proj_w, Wp, n4);
  }
  {
    int n = SEQ * HD;
    trig_tab<<<(n + 255) / 256, 256, 0, stream>>>(rope, ct, st, n);
  }
  gemm_bt<0><<<dim3(TDIM / 128, SEQ / 128), 256, 0, stream>>>(Xb, Wq, qkv_b, Y, SEQ, TDIM, DIM);
  rope_qk<<<dim3(NH, SEQ), 128, 0, stream>>>(Y, ct, st, Qr, Kr);
  vtrans<<<NH * HD, 256, 0, stream>>>(Y, Vt);
  attn3<<<dim3(SEQ / 128, NH), 256, 0, stream>>>(Qr, Kr, Vt, Ob);
  gemm_bt<1><<<dim3(DIM / 128, SEQ / 128), 256, 0, stream>>>(Ob, Wp, proj_b, d_out, SEQ, DIM, DIM);
}

// Round 4
// 293.862 us; speedup vs baseline: 2.2271x; 1.0910x over previous
//
#include <hip/hip_runtime.h>

#define SEQ 4096
#define DIM 1280
#define NH 16
#define HD 80
#define HQ 96
#define TDIM 3840

// softmax scale (1/sqrt(80)) * log2(e), folded into Q at repack
#define QSC 0.16129842980505168f

typedef __bf16 bf16x8 __attribute__((ext_vector_type(8)));
typedef __bf16 bf16x4 __attribute__((ext_vector_type(4)));
typedef float f32x4 __attribute__((ext_vector_type(4)));

__device__ __forceinline__ unsigned short f2bf(float f) {
  unsigned int u = __builtin_bit_cast(unsigned int, f);
  u += 0x7FFF + ((u >> 16) & 1);
  return (unsigned short)(u >> 16);
}
__device__ __forceinline__ float bf2f(unsigned short b) {
  unsigned int u = ((unsigned int)b) << 16;
  return __builtin_bit_cast(float, u);
}
__device__ __forceinline__ unsigned int cvtpk(float a, float b) {
  unsigned int r;
  asm("v_cvt_pk_bf16_f32 %0, %1, %2" : "=v"(r) : "v"(a), "v"(b));
  return r;
}

__device__ __forceinline__ void gload_lds16(const void* g, void* l) {
  __builtin_amdgcn_global_load_lds(
      (const __attribute__((address_space(1))) unsigned int*)g,
      (__attribute__((address_space(3))) unsigned int*)l, 16, 0, 0);
}

// ---------------- fp32 -> bf16 convert (vectorized) ----------------
__global__ void cvt_bf16(const float* __restrict__ in, unsigned short* __restrict__ out, int n4) {
  int i = blockIdx.x * 256 + threadIdx.x;
  if (i >= n4) return;
  float4 f = ((const float4*)in)[i];
  ushort4 o;
  o.x = f2bf(f.x); o.y = f2bf(f.y); o.z = f2bf(f.z); o.w = f2bf(f.w);
  ((ushort4*)out)[i] = o;
}

// ---------------- cos/sin table ----------------
__global__ void trig_tab(const float* __restrict__ rope, float* __restrict__ ct,
                         float* __restrict__ st, int n) {
  int i = blockIdx.x * 256 + threadIdx.x;
  if (i >= n) return;
  float v = rope[i];
  ct[i] = cosf(v);
  st[i] = sinf(v);
}

// ---------------- GEMM: C = A(MxK) @ B(NxK)^T + bias ----------------
template <int F32OUT>
__global__ __launch_bounds__(256) void gemm_bt(const unsigned short* __restrict__ A,
                                               const unsigned short* __restrict__ B,
                                               const float* __restrict__ bias,
                                               void* __restrict__ Cout, int M, int N, int K) {
  __shared__ unsigned short As[4096];
  __shared__ unsigned short Bs[4096];
  const int t = threadIdx.x;
  const int l = t & 63, w = t >> 6;
  const int row16 = l & 15, kg = l >> 4;
  const int brow = blockIdx.y * 128, bcol = blockIdx.x * 128;
  const int wr = w >> 1, wc = w & 1;
  f32x4 acc[4][4] = {};
  const size_t Ks = (size_t)K;
  const unsigned short* Ag = A + (brow + (t >> 2)) * Ks + (t & 3) * 8;
  const unsigned short* Bg = B + (bcol + (t >> 2)) * Ks + (t & 3) * 8;
  unsigned short* AsW = As + w * 512;
  unsigned short* BsW = Bs + w * 512;
  const int nk = K >> 5;
  for (int kt = 0; kt < nk; ++kt) {
    const unsigned short* a = Ag + kt * 32;
    const unsigned short* b = Bg + kt * 32;
    gload_lds16(a, AsW);
    gload_lds16(a + 64 * Ks, AsW + 2048);
    gload_lds16(b, BsW);
    gload_lds16(b + 64 * Ks, BsW + 2048);
    __syncthreads();
    bf16x8 af[4], bfr[4];
#pragma unroll
    for (int m = 0; m < 4; ++m)
      af[m] = *(const bf16x8*)&As[(wr * 64 + m * 16 + row16) * 32 + kg * 8];
#pragma unroll
    for (int n = 0; n < 4; ++n)
      bfr[n] = *(const bf16x8*)&Bs[(wc * 64 + n * 16 + row16) * 32 + kg * 8];
#pragma unroll
    for (int m = 0; m < 4; ++m)
#pragma unroll
      for (int n = 0; n < 4; ++n)
        acc[m][n] = __builtin_amdgcn_mfma_f32_16x16x32_bf16(af[m], bfr[n], acc[m][n], 0, 0, 0);
    __syncthreads();
  }
#pragma unroll
  for (int n = 0; n < 4; ++n) {
    const int col = bcol + wc * 64 + n * 16 + row16;
    const float bv = bias[col];
#pragma unroll
    for (int m = 0; m < 4; ++m) {
      const int row = brow + wr * 64 + m * 16 + kg * 4;
#pragma unroll
      for (int r = 0; r < 4; ++r) {
        float v = acc[m][n][r] + bv;
        if (F32OUT)
          ((float*)Cout)[(size_t)(row + r) * N + col] = v;
        else
          ((unsigned short*)Cout)[(size_t)(row + r) * N + col] = f2bf(v);
      }
    }
  }
}

// ---------------- RoPE + repack Q,K -> [h][s][96]; Q pre-scaled ----------------
// one block per s; pair-wise (d, d+40) so each input is loaded once
__global__ __launch_bounds__(256) void rope_qk2(const unsigned short* __restrict__ Y,
                                                const float* __restrict__ ct,
                                                const float* __restrict__ st,
                                                unsigned short* __restrict__ Qr,
                                                unsigned short* __restrict__ Kr) {
  const int s = blockIdx.x, tid = threadIdx.x;
  const unsigned short* yq = Y + (size_t)s * TDIM;
  const unsigned short* yk = yq + DIM;
  for (int i = tid; i < 640; i += 256) {
    const int h = i / 40, j = i - h * 40;
    const float c0 = ct[s * HD + j], c1 = ct[s * HD + j + 40];
    const float s0 = st[s * HD + j], s1 = st[s * HD + j + 40];
    const float q0 = bf2f(yq[h * HD + j]), q1 = bf2f(yq[h * HD + j + 40]);
    const float k0 = bf2f(yk[h * HD + j]), k1 = bf2f(yk[h * HD + j + 40]);
    const size_t o = ((size_t)h * SEQ + s) * HQ;
    Qr[o + j] = f2bf((q0 * c0 - q1 * s0) * QSC);
    Qr[o + j + 40] = f2bf((q1 * c1 + q0 * s1) * QSC);
    Kr[o + j] = f2bf(k0 * c0 - k1 * s0);
    Kr[o + j + 40] = f2bf(k1 * c1 + k0 * s1);
  }
  {  // zero pad d = 80..95 for all 16 heads
    const int h = tid >> 4, dp = 80 + (tid & 15);
    const size_t o = ((size_t)h * SEQ + s) * HQ + dp;
    Qr[o] = 0;
    Kr[o] = 0;
  }
}

// ---------------- V transpose via LDS tile -> [h][d=80][s] ----------------
// 64s x 80d tile; coalesced 16B reads and writes; XOR-swizzled LDS
__global__ __launch_bounds__(256) void vtrans2(const unsigned short* __restrict__ Y,
                                               unsigned short* __restrict__ Vt) {
  __shared__ unsigned short tile[64][128];
  const int h = blockIdx.x, s0 = blockIdx.y * 64, tid = threadIdx.x;
  const unsigned short* src = Y + 2 * DIM + h * HD;
  for (int u = tid; u < 640; u += 256) {
    const int s = u / 10, j = u - s * 10;
    uint4 v = *(const uint4*)(src + (size_t)(s0 + s) * TDIM + j * 8);
    *(uint4*)&tile[s][(j ^ ((s >> 3) & 7)) << 3] = v;
  }
  __syncthreads();
  for (int u = tid; u < 640; u += 256) {
    const int d = u >> 3, sg = u & 7;
    unsigned short tmp[8];
#pragma unroll
    for (int k = 0; k < 8; ++k)
      tmp[k] = tile[sg * 8 + k][((((d >> 3) ^ sg) << 3)) + (d & 7)];
    *(uint4*)(Vt + (size_t)(h * HD + d) * SEQ + s0 + sg * 8) = *(uint4*)tmp;
  }
}

// ---------------- Flash attention v4: 8 waves x 16 q-rows, dbuf LDS staging ----
// grid: 512 blocks 1-D; h = bid&15 (head -> XCD affinity), q-chunk = bid>>4.
// K LDS rows padded to 256B, XOR-swizzled on 16B granules; V rows 128B same.
__global__ __launch_bounds__(512, 4) void attn4(const unsigned short* __restrict__ Qr,
                                                const unsigned short* __restrict__ Kr,
                                                const unsigned short* __restrict__ Vt,
                                                unsigned short* __restrict__ Ob) {
  constexpr int KBYT = 64 * 256;     // 16384
  constexpr int VBYT = 80 * 128;     // 10240
  constexpr int BUFB = KBYT + VBYT;  // 26624
  __shared__ char smem[2 * BUFB];

  const int tid = threadIdx.x;
  const int l = tid & 63, w = tid >> 6;
  const int row16 = l & 15, kg = l >> 4;
  const int bid = blockIdx.x;
  const int h = bid & 15;
  const int q0 = (bid >> 4) * 128 + w * 16;
  const size_t hs = (size_t)h * SEQ;

  const unsigned short* Qh = Qr + hs * HQ;
  const char* Kh = (const char*)(Kr + hs * HQ);
  const char* Vh = (const char*)(Vt + (size_t)h * HD * SEQ);

  // staging: 1664 16B-units (1024 K + 640 V), unit u = tid + 512*i
  unsigned soff[4], sdst[4];
  bool isk[4];
  const int cnt = (tid < 128) ? 4 : 3;
#pragma unroll
  for (int i = 0; i < 4; ++i) {
    const int u = tid + 512 * i;
    if (u < 1024) {
      const int r = u >> 4, g = u & 15;
      soff[i] = r * 192 + ((g ^ (r & 7)) << 4);
      isk[i] = true;
    } else {
      const int vu = u - 1024;
      const int d = vu >> 3, g = vu & 7;
      soff[i] = d * 8192 + ((g ^ (d & 7)) << 4);
      isk[i] = false;
    }
    sdst[i] = u << 4;
  }
  auto STAGE = [&](int t, int bb) {
    const char* kb = Kh + (size_t)t * 12288;
    const char* vb = Vh + (size_t)t * 128;
#pragma unroll
    for (int i = 0; i < 4; ++i)
      if (i < cnt) gload_lds16((isk[i] ? kb : vb) + soff[i], smem + bb + sdst[i]);
  };

  // LDS read bases (tile-invariant)
  const int swl = (row16 & 7) << 4;
  int kb_[3];
#pragma unroll
  for (int c = 0; c < 3; ++c) kb_[c] = row16 * 256 + ((c * 64 + kg * 16) ^ swl);
  int vb_[2][2];
#pragma unroll
  for (int ks = 0; ks < 2; ++ks)
#pragma unroll
    for (int h2 = 0; h2 < 2; ++h2)
      vb_[ks][h2] = KBYT + row16 * 128 + ((kg * 8 + ks * 64 + h2 * 32) ^ swl);

  // Q fragments (B-operand of swapped QK^T): q = q0 + row16
  bf16x8 qf[3];
#pragma unroll
  for (int c = 0; c < 3; ++c)
    qf[c] = *(const bf16x8*)&Qh[(size_t)(q0 + row16) * HQ + c * 32 + kg * 8];

  union { bf16x8 v; unsigned int u[4]; } ones;
  ones.u[0] = ones.u[1] = ones.u[2] = ones.u[3] = 0x3F803F80u;

  float m_run = -3.0e38f;
  f32x4 oacc[6] = {};  // [d-block 0..4, 5 = row-sum l]

  STAGE(0, 0);
  __syncthreads();

#pragma unroll 1
  for (int t = 0; t < SEQ / 64; ++t) {
    const int cur = t & 1;
    if (t + 1 < SEQ / 64) STAGE(t + 1, (cur ^ 1) * BUFB);
    const char* B = smem + cur * BUFB;
    // K fragments
    bf16x8 kf[4][3];
#pragma unroll
    for (int nb = 0; nb < 4; ++nb)
#pragma unroll
      for (int c = 0; c < 3; ++c) kf[nb][c] = *(const bf16x8*)(B + kb_[c] + nb * 4096);
    // S^T = K . Q^T : lane holds 16 scores for q = q0+row16
    f32x4 sacc[4] = {};
    __builtin_amdgcn_s_setprio(1);
#pragma unroll
    for (int c = 0; c < 3; ++c)
#pragma unroll
      for (int nb = 0; nb < 4; ++nb)
        sacc[nb] = __builtin_amdgcn_mfma_f32_16x16x32_bf16(kf[nb][c], qf[c], sacc[nb], 0, 0, 0);
    __builtin_amdgcn_s_setprio(0);
    // V fragments (permuted k-map: slot j of lane kg <-> s_local = ks*32+(j>>2)*16+kg*4+(j&3))
    union { bf16x8 v8; bf16x4 h4[2]; } vf[5][2];
#pragma unroll
    for (int n5 = 0; n5 < 5; ++n5)
#pragma unroll
      for (int ks = 0; ks < 2; ++ks) {
        vf[n5][ks].h4[0] = *(const bf16x4*)(B + vb_[ks][0] + n5 * 2048);
        vf[n5][ks].h4[1] = *(const bf16x4*)(B + vb_[ks][1] + n5 * 2048);
      }
    // per-lane softmax, cross-lane only over kg
    float a0 = fmaxf(fmaxf(sacc[0][0], sacc[0][1]), fmaxf(sacc[0][2], sacc[0][3]));
    float a1 = fmaxf(fmaxf(sacc[1][0], sacc[1][1]), fmaxf(sacc[1][2], sacc[1][3]));
    float a2 = fmaxf(fmaxf(sacc[2][0], sacc[2][1]), fmaxf(sacc[2][2], sacc[2][3]));
    float a3 = fmaxf(fmaxf(sacc[3][0], sacc[3][1]), fmaxf(sacc[3][2], sacc[3][3]));
    float m0 = fmaxf(fmaxf(a0, a1), fmaxf(a2, a3));
    m0 = fmaxf(m0, __shfl_xor(m0, 16, 64));
    m0 = fmaxf(m0, __shfl_xor(m0, 32, 64));
    if (!__all(m0 - m_run <= 8.0f)) {
      const float mn = fmaxf(m_run, m0);
      const float fac = __builtin_amdgcn_exp2f(m_run - mn);
      m_run = mn;
#pragma unroll
      for (int n6 = 0; n6 < 6; ++n6)
#pragma unroll
        for (int r = 0; r < 4; ++r) oacc[n6][r] *= fac;
    }
#pragma unroll
    for (int nb = 0; nb < 4; ++nb)
#pragma unroll
      for (int r = 0; r < 4; ++r) sacc[nb][r] = __builtin_amdgcn_exp2f(sacc[nb][r] - m_run);
    // pack P -> bf16 (same permuted k-map as V) and PV + row-sum
    __builtin_amdgcn_s_setprio(1);
#pragma unroll
    for (int ks = 0; ks < 2; ++ks) {
      union { bf16x8 v; unsigned int u[4]; } pf;
      pf.u[0] = cvtpk(sacc[2 * ks][0], sacc[2 * ks][1]);
      pf.u[1] = cvtpk(sacc[2 * ks][2], sacc[2 * ks][3]);
      pf.u[2] = cvtpk(sacc[2 * ks + 1][0], sacc[2 * ks + 1][1]);
      pf.u[3] = cvtpk(sacc[2 * ks + 1][2], sacc[2 * ks + 1][3]);
#pragma unroll
      for (int n5 = 0; n5 < 5; ++n5)
        oacc[n5] = __builtin_amdgcn_mfma_f32_16x16x32_bf16(vf[n5][ks].v8, pf.v, oacc[n5], 0, 0, 0);
      oacc[5] = __builtin_amdgcn_mfma_f32_16x16x32_bf16(ones.v, pf.v, oacc[5], 0, 0, 0);
    }
    __builtin_amdgcn_s_setprio(0);
    __syncthreads();
  }
  // epilogue: d = n5*16 + kg*4 + r, q = q0 + row16
  const float rl = 1.0f / oacc[5][0];
  unsigned short* orow = Ob + (size_t)(q0 + row16) * DIM + h * HD + kg * 4;
#pragma unroll
  for (int n5 = 0; n5 < 5; ++n5) {
    ushort4 o;
    o.x = f2bf(oacc[n5][0] * rl);
    o.y = f2bf(oacc[n5][1] * rl);
    o.z = f2bf(oacc[n5][2] * rl);
    o.w = f2bf(oacc[n5][3] * rl);
    *(ushort4*)(orow + n5 * 16) = o;
  }
}

// ---------------- host ----------------
extern "C" void kernel_launch(void* const* d_in, const int* in_sizes, int n_in, void* d_out,
                              int out_size, void* d_ws, size_t ws_size, hipStream_t stream) {
  (void)in_sizes; (void)n_in; (void)out_size; (void)ws_size;
  const float* hidden = (const float*)d_in[0];
  const float* rope = (const float*)d_in[2];
  const float* qkv_w = (const float*)d_in[3];
  const float* qkv_b = (const float*)d_in[4];
  const float* proj_w = (const float*)d_in[5];
  const float* proj_b = (const float*)d_in[6];

  char* p = (char*)d_ws;
  unsigned short* Xb = (unsigned short*)p;       p += (size_t)SEQ * DIM * 2;
  unsigned short* Wq = (unsigned short*)p;       p += (size_t)TDIM * DIM * 2;
  unsigned short* Wp = (unsigned short*)p;       p += (size_t)DIM * DIM * 2;
  float* ct = (float*)p;                         p += (size_t)SEQ * HD * 4;
  float* st = (float*)p;                         p += (size_t)SEQ * HD * 4;
  unsigned short* Y = (unsigned short*)p;        p += (size_t)SEQ * TDIM * 2;
  unsigned short* Qr = (unsigned short*)p;       p += (size_t)NH * SEQ * HQ * 2;
  unsigned short* Kr = (unsigned short*)p;       p += (size_t)NH * SEQ * HQ * 2;
  unsigned short* Vt = (unsigned short*)p;       p += (size_t)NH * HD * SEQ * 2;
  unsigned short* Ob = (unsigned short*)p;       p += (size_t)SEQ * DIM * 2;

  {
    int n4 = SEQ * DIM / 4;
    cvt_bf16<<<(n4 + 255) / 256, 256, 0, stream>>>(hidden, Xb, n4);
  }
  {
    int n4 = TDIM * DIM / 4;
    cvt_bf16<<<(n4 + 255) / 256, 256, 0, stream>>>(qkv_w, Wq, n4);
  }
  {
    int n4 = DIM * DIM / 4;
    cvt_bf16<<<(n4 + 255) / 256, 256, 0, stream>>>(proj_w, Wp, n4);
  }
  {
    int n = SEQ * HD;
    trig_tab<<<(n + 255) / 256, 256, 0, stream>>>(rope, ct, st, n);
  }
  gemm_bt<0><<<dim3(TDIM / 128, SEQ / 128), 256, 0, stream>>>(Xb, Wq, qkv_b, Y, SEQ, TDIM, DIM);
  rope_qk2<<<SEQ, 256, 0, stream>>>(Y, ct, st, Qr, Kr);
  vtrans2<<<dim3(NH, SEQ / 64), 256, 0, stream>>>(Y, Vt);
  attn4<<<512, 512, 0, stream>>>(Qr, Kr, Vt, Ob);
  gemm_bt<1><<<dim3(DIM / 128, SEQ / 128), 256, 0, stream>>>(Ob, Wp, proj_b, d_out, SEQ, DIM, DIM);
}